// Round 6
// baseline (115.524 us; speedup 1.0000x reference)
//
#include <hip/hip_runtime.h>
#include <hip/hip_bf16.h>

// Shapes (fixed): B=4, T=64, L=128, D=768, H=12, d=64
#define NB 4
#define NT 64
#define NL 128
#define ND 768
#define NH 12
#define HD 64

typedef __attribute__((ext_vector_type(8))) short short8;
typedef __attribute__((ext_vector_type(4))) float f32x4;

typedef __attribute__((address_space(3))) unsigned int lds_u32;
typedef __attribute__((address_space(1))) const unsigned int glob_u32;

static __device__ __forceinline__ unsigned short f2b(float x) {
    __hip_bfloat16 h = __float2bfloat16(x);
    return *reinterpret_cast<unsigned short*>(&h);
}
static __device__ __forceinline__ float b2f(unsigned short u) {
    unsigned int v = ((unsigned int)u) << 16;
    union { unsigned int i; float f; } c; c.i = v; return c.f;
}
// async global->LDS, 16B/lane; LDS dest = base + lane*16 (wave-uniform base)
static __device__ __forceinline__ void gl2lds16(const void* g, void* l) {
    __builtin_amdgcn_global_load_lds((glob_u32*)g, (lds_u32*)l, 16, 0, 0);
}

// conversion chunk boundaries (8-float chunks): te | Wq | edu | Wk | Wv
#define TE_C   3145728u
#define WQ_C   3219456u
#define EDU_C  3244032u
#define WK_C   3317760u
#define NCHUNK 3391488u

// ---------------------------------------------------------------------------
// Kernel 1: streaming fp32 -> bf16 of te, Wq, edu, Wk, Wv (concatenated dst).
// ---------------------------------------------------------------------------
__global__ __launch_bounds__(256) void conv_bf16(
    const float* __restrict__ te, const float* __restrict__ Wq,
    const float* __restrict__ edu, const float* __restrict__ Wk,
    const float* __restrict__ Wv, unsigned short* __restrict__ dst)
{
    for (size_t c = (size_t)blockIdx.x * 256 + threadIdx.x; c < (size_t)NCHUNK;
         c += (size_t)2048 * 256) {
        const float* s;
        if (c < TE_C)       s = te  + c * 8;
        else if (c < WQ_C)  s = Wq  + (c - TE_C)  * 8;
        else if (c < EDU_C) s = edu + (c - WQ_C)  * 8;
        else if (c < WK_C)  s = Wk  + (c - EDU_C) * 8;
        else                s = Wv  + (c - WK_C)  * 8;
        float4 x = *(const float4*)s;
        float4 y = *(const float4*)(s + 4);
        unsigned short v[8];
        v[0] = f2b(x.x); v[1] = f2b(x.y); v[2] = f2b(x.z); v[3] = f2b(x.w);
        v[4] = f2b(y.x); v[5] = f2b(y.y); v[6] = f2b(y.z); v[7] = f2b(y.w);
        *(short8*)(dst + c * 8) = *(short8*)v;
    }
}

// ---------------------------------------------------------------------------
// Kernel 2: fused K/V projection (bf16 MFMA) + speaker-bucket prefix scan.
// (unchanged — verified rounds 4/5)
// ---------------------------------------------------------------------------
__global__ __launch_bounds__(256) void kvm(
    const unsigned short* __restrict__ edu_b,
    const unsigned short* __restrict__ wk_b,
    const unsigned short* __restrict__ wv_b,
    const int* __restrict__ spk,
    unsigned short* __restrict__ Mt)
{
    const int h = blockIdx.x, b = blockIdx.y, eh = blockIdx.z;

    __shared__ float bucket[8][32][65];
    __shared__ float k_s[64][68];
    __shared__ float v_s[64][36];
    __shared__ __align__(16) unsigned short stage[10240];
    __shared__ int spk_s[64];
    unsigned short* edu_s = stage;
    unsigned short* wk_s  = stage + 4096;
    unsigned short* wv_s  = stage + 8192;

    const int tid = threadIdx.x, lane = tid & 63, wvx = tid >> 6;
    const int lr = lane & 15, lg = lane >> 4, r8 = lane >> 3, l8 = lane & 7;

    { float* p = &bucket[0][0][0];
      for (int i = tid; i < 8 * 32 * 65; i += 256) p[i] = 0.f; }
    if (tid < 64) spk_s[tid] = spk[b * NT + tid];

    const unsigned short* edub = edu_b + (size_t)(b * 64) * ND;
    const unsigned short* wkb  = wk_b + (size_t)(h * 64) * ND;
    const unsigned short* wvb  = wv_b + (size_t)(h * 64 + eh * 32) * ND;

    f32x4 acc_k[4], acc_v[2];
    #pragma unroll
    for (int i = 0; i < 4; i++) acc_k[i] = (f32x4){0.f, 0.f, 0.f, 0.f};
    #pragma unroll
    for (int i = 0; i < 2; i++) acc_v[i] = (f32x4){0.f, 0.f, 0.f, 0.f};

    const int sswz = ((l8 ^ r8) * 8);

    for (int k0 = 0; k0 < ND; k0 += 64) {
        __syncthreads();
        #pragma unroll
        for (int j = 0; j < 5; j++) {
            const int cid = wvx * 5 + j;
            const unsigned short* gs; unsigned short* ls;
            if (cid < 8)       { gs = edub + (size_t)(cid * 8 + r8) * ND;        ls = edu_s + cid * 512; }
            else if (cid < 16) { gs = wkb  + (size_t)((cid - 8) * 8 + r8) * ND;  ls = wk_s + (cid - 8) * 512; }
            else               { gs = wvb  + (size_t)((cid - 16) * 8 + r8) * ND; ls = wv_s + (cid - 16) * 512; }
            gl2lds16(gs + k0 + sswz, ls);
        }
        __syncthreads();
        #pragma unroll
        for (int k32 = 0; k32 < 2; k32++) {
            const int cx = (((k32 * 4 + lg) ^ (lr & 7)) * 8);
            short8 eb = *(const short8*)&edu_s[(wvx * 16 + lr) * 64 + cx];
            #pragma unroll
            for (int jb = 0; jb < 4; jb++) {
                short8 ak = *(const short8*)&wk_s[(jb * 16 + lr) * 64 + cx];
                acc_k[jb] = __builtin_amdgcn_mfma_f32_16x16x32_bf16(ak, eb, acc_k[jb], 0, 0, 0);
            }
            #pragma unroll
            for (int jb = 0; jb < 2; jb++) {
                short8 av = *(const short8*)&wv_s[(jb * 16 + lr) * 64 + cx];
                acc_v[jb] = __builtin_amdgcn_mfma_f32_16x16x32_bf16(av, eb, acc_v[jb], 0, 0, 0);
            }
        }
    }

    {
        const int t = wvx * 16 + lr;
        #pragma unroll
        for (int jb = 0; jb < 4; jb++) *(f32x4*)&k_s[t][jb * 16 + lg * 4] = acc_k[jb];
        #pragma unroll
        for (int jb = 0; jb < 2; jb++) *(f32x4*)&v_s[t][jb * 16 + lg * 4] = acc_v[jb];
    }
    __syncthreads();

    const int e = tid & 31, dg = tid >> 5;
    for (int t = 0; t < NT; t++) {
        const int s = spk_s[t];
        const float vv = v_s[t][e];
        unsigned short tmp[8];
        #pragma unroll
        for (int jj = 0; jj < 8; jj++) {
            float m = bucket[s][e][dg * 8 + jj] + k_s[t][dg * 8 + jj] * vv;
            bucket[s][e][dg * 8 + jj] = m;
            tmp[jj] = f2b(m);
        }
        unsigned short* mpp = Mt + (((size_t)(b * NT + t) * NH + h) * HD + eh * 32 + e) * HD + dg * 8;
        *(short8*)mpp = *(short8*)tmp;
    }
}

// ---------------------------------------------------------------------------
// Kernel 3: fused bf16 MFMA  q^T = Wq_hp @ te^T (K=768), a = q @ M, residual.
// Round-4 structure + T3-minimum double-buffered prefetch:
//   STAGE(next tile, other buf) issued BEFORE compute of current tile;
//   ONE __syncthreads per k-tile (its vmcnt(0) drain = stage-completion wait).
// LDS 80 KB: buf0 [0,16384) buf1 [16384,32768) (te 8192 + wq 8192 ush each),
//            mt_s [32768,40960); phase 2 reuses [0,17408) as q_s.
// ---------------------------------------------------------------------------
__global__ __launch_bounds__(256, 2) void fused_qm(
    const unsigned short* __restrict__ te_b,
    const unsigned short* __restrict__ wq_b,
    const unsigned short* __restrict__ Mt,
    float* __restrict__ out)
{
    const int orig = blockIdx.x;
    const int id   = (orig & 7) * 192 + (orig >> 3);   // bijective XCD swizzle
    const int hp   = id % 6;
    const int bt   = id / 6;

    __shared__ __align__(16) unsigned short smem[40960];
    unsigned short* mt_s = smem + 32768;
    unsigned short* q_s  = smem;

    const int tid  = threadIdx.x;
    const int lane = tid & 63;
    const int wvx  = tid >> 6;
    const int lr   = lane & 15;
    const int lg   = lane >> 4;
    const int wm   = wvx >> 1;
    const int wn   = wvx & 1;
    const int r8   = lane >> 3;
    const int l8   = lane & 7;
    const int sswz = (l8 ^ r8) * 8;     // pre-swizzled source chunk (ush)

    const unsigned short* teb = te_b + (size_t)bt * NL * ND;
    const unsigned short* wqb = wq_b + (size_t)hp * 128 * ND;

    // ---- prefetch Mt (2 heads, 16 KB) -> mt_s (swizzled rows of 64 ush) ----
    {
        const unsigned short* mp = Mt + ((size_t)bt * NH + hp * 2) * (HD * HD);
        #pragma unroll
        for (int j = 0; j < 4; j++) {
            const int off = wvx * 2048 + j * 512;
            gl2lds16(mp + off + r8 * 64 + sswz, mt_s + off);
        }
    }

    f32x4 acc[4][4];
    #pragma unroll
    for (int i = 0; i < 4; i++)
        #pragma unroll
        for (int j = 0; j < 4; j++) acc[i][j] = (f32x4){0.f, 0.f, 0.f, 0.f};

    // stage one 64-wide k-tile of te+wq into buffer at ush-offset bb
    auto STAGE = [&](int bb, int k0) {
        #pragma unroll
        for (int j = 0; j < 4; j++) {
            const int rbase = wvx * 32 + j * 8;   // wave-uniform dest base
            gl2lds16(teb + (size_t)(rbase + r8) * ND + k0 + sswz,
                     smem + bb + rbase * 64);
            gl2lds16(wqb + (size_t)(rbase + r8) * ND + k0 + sswz,
                     smem + bb + 8192 + rbase * 64);
        }
    };
    // MFMA over one staged 64-wide k-tile
    auto COMPUTE = [&](int bb) {
        const unsigned short* tes = smem + bb;
        const unsigned short* wqs = smem + bb + 8192;
        #pragma unroll
        for (int k32 = 0; k32 < 2; k32++) {
            const int cx = (((k32 * 4 + lg) ^ (lr & 7)) * 8);
            short8 af[4], bf[4];
            #pragma unroll
            for (int tm = 0; tm < 4; tm++)
                af[tm] = *(const short8*)&wqs[(wm * 64 + tm * 16 + lr) * 64 + cx];
            #pragma unroll
            for (int tn = 0; tn < 4; tn++)
                bf[tn] = *(const short8*)&tes[(wn * 64 + tn * 16 + lr) * 64 + cx];
            #pragma unroll
            for (int tm = 0; tm < 4; tm++)
                #pragma unroll
                for (int tn = 0; tn < 4; tn++)
                    acc[tm][tn] = __builtin_amdgcn_mfma_f32_16x16x32_bf16(
                        af[tm], bf[tn], acc[tm][tn], 0, 0, 0);
        }
    };

    // ---- GEMM1 K-loop, double-buffered (static buffer indices) ----
    STAGE(0, 0);
    __syncthreads();                    // drains vmcnt: tile0 + Mt ready
    for (int k0 = 0; k0 < ND; k0 += 128) {
        STAGE(16384, k0 + 64);          // k0+64 <= 704 always valid
        COMPUTE(0);
        __syncthreads();                // vmcnt(0): buf1 ready
        if (k0 + 128 < ND) STAGE(0, k0 + 128);
        COMPUTE(16384);
        __syncthreads();                // vmcnt(0): buf0 ready
    }

    // ---- q^T C-frags -> row-major bf16 q_s[l][d] (8B packed writes) ----
    #pragma unroll
    for (int tm = 0; tm < 4; tm++) {
        const int d0 = wm * 64 + tm * 16 + lg * 4;
        #pragma unroll
        for (int tn = 0; tn < 4; tn++) {
            const int ltok = wn * 64 + tn * 16 + lr;
            f32x4 a = acc[tm][tn];
            uint2 w2;
            w2.x = (unsigned)f2b(a.x) | ((unsigned)f2b(a.y) << 16);
            w2.y = (unsigned)f2b(a.z) | ((unsigned)f2b(a.w) << 16);
            *(uint2*)&q_s[ltok * 136 + d0] = w2;
        }
    }
    __syncthreads();

    // ---- GEMM2: per-wave one (token-half, head), 64x64, K=64 ----
    const int h2 = wvx & 1;
    const int lh = wvx >> 1;
    f32x4 acc2[4][4];
    #pragma unroll
    for (int i = 0; i < 4; i++)
        #pragma unroll
        for (int j = 0; j < 4; j++) acc2[i][j] = (f32x4){0.f, 0.f, 0.f, 0.f};

    #pragma unroll
    for (int k32 = 0; k32 < 2; k32++) {
        const int ko = k32 * 32 + lg * 8;
        const int cx = (((k32 * 4 + lg) ^ (lr & 7)) * 8);
        short8 af[4], bf[4];
        #pragma unroll
        for (int tm = 0; tm < 4; tm++)
            af[tm] = *(const short8*)&q_s[(lh * 64 + tm * 16 + lr) * 136 + h2 * 64 + ko];
        #pragma unroll
        for (int tn = 0; tn < 4; tn++)
            bf[tn] = *(const short8*)&mt_s[(h2 * 64 + tn * 16 + lr) * 64 + cx];
        #pragma unroll
        for (int tm = 0; tm < 4; tm++)
            #pragma unroll
            for (int tn = 0; tn < 4; tn++)
                acc2[tm][tn] = __builtin_amdgcn_mfma_f32_16x16x32_bf16(
                    af[tm], bf[tn], acc2[tm][tn], 0, 0, 0);
    }

    // ---- epilogue: out = bf16(te) + a (te_b L2-hot from staging) ----
    float* ob = out + (size_t)bt * NL * ND;
    #pragma unroll
    for (int tm = 0; tm < 4; tm++) {
        const int l0 = lh * 64 + tm * 16 + lg * 4;
        #pragma unroll
        for (int tn = 0; tn < 4; tn++) {
            const int cg = hp * 128 + h2 * 64 + tn * 16 + lr;
            f32x4 a = acc2[tm][tn];
            #pragma unroll
            for (int r = 0; r < 4; r++) {
                size_t gi = (size_t)(l0 + r) * ND + cg;
                ob[gi] = b2f(teb[gi]) + a[r];
            }
        }
    }
}

// ---------------------------------------------------------------------------
extern "C" void kernel_launch(void* const* d_in, const int* in_sizes, int n_in,
                              void* d_out, int out_size, void* d_ws, size_t ws_size,
                              hipStream_t stream)
{
    const int*   spk = (const int*)d_in[1];
    const float* te  = (const float*)d_in[2];
    const float* edu = (const float*)d_in[3];
    const float* Wk  = (const float*)d_in[4];
    const float* Wv  = (const float*)d_in[5];
    const float* Wq  = (const float*)d_in[6];
    float* out = (float*)d_out;

    // ws layout (ush units), ~79.4 MB total:
    unsigned short* bf    = (unsigned short*)d_ws;
    unsigned short* te_bb = bf;                          // 25165824
    unsigned short* wq_bb = bf + 25165824u;              //   589824
    unsigned short* edu_b = bf + 25755648u;              //   196608
    unsigned short* wk_bb = bf + 25952256u;              //   589824
    unsigned short* wv_bb = bf + 26542080u;              //   589824
    unsigned short* Mtbuf = bf + 27131904u;              // 12582912

    conv_bf16<<<2048,            256, 0, stream>>>(te, Wq, edu, Wk, Wv, bf);
    kvm      <<<dim3(NH, NB, 2), 256, 0, stream>>>(edu_b, wk_bb, wv_bb, spk, Mtbuf);
    fused_qm <<<6 * NT * NB,     256, 0, stream>>>(te_bb, wq_bb, Mtbuf, out);
}